// Round 2
// baseline (193.089 us; speedup 1.0000x reference)
//
#include <hip/hip_runtime.h>

#define NB   16
#define INF  512
#define OUTF 512

typedef __attribute__((ext_vector_type(8))) short bf16x8;
typedef __attribute__((ext_vector_type(4))) float f32x4;

static __device__ __forceinline__ ushort f2bf(float f) {
    unsigned u = __float_as_uint(f);
    u += 0x7FFFu + ((u >> 16) & 1u);   // round-to-nearest-even
    return (ushort)(u >> 16);
}

// ---------------- Kernel 1: prep ----------------
// block 0           : bucket rows by bank (16 serial scanner lanes, no atomics)
// blocks 1..gridDim : convert W then x to bf16 (grid-stride float4 -> ushort4)
__global__ __launch_bounds__(256) void prep_kernel(
    const float* __restrict__ x, const int* __restrict__ sel,
    const float* __restrict__ W,
    int* __restrict__ counts, int* __restrict__ lists,
    ushort* __restrict__ xb, ushort* __restrict__ Wb, int nrows)
{
    int t = threadIdx.x;
    if (blockIdx.x == 0) {
        if (t < NB) {
            int c = 0;
            for (int r = 0; r < nrows; ++r)
                if (sel[r] == t) lists[t * nrows + c++] = r;
            counts[t] = c;
        }
        return;
    }
    const int nvw = NB * OUTF * INF / 4;
    const int nvx = (nrows * INF) / 4;
    int gid = (blockIdx.x - 1) * 256 + t;
    int stride = (gridDim.x - 1) * 256;
    const float4* Wf = (const float4*)W;
    const float4* xf = (const float4*)x;
    ushort4* Wo = (ushort4*)Wb;
    ushort4* xo = (ushort4*)xb;
    for (int i = gid; i < nvw + nvx; i += stride) {
        if (i < nvw) {
            float4 v = Wf[i];
            ushort4 o;
            o.x = f2bf(v.x); o.y = f2bf(v.y); o.z = f2bf(v.z); o.w = f2bf(v.w);
            Wo[i] = o;
        } else {
            int j = i - nvw;
            float4 v = xf[j];
            ushort4 o;
            o.x = f2bf(v.x); o.y = f2bf(v.y); o.z = f2bf(v.z); o.w = f2bf(v.w);
            xo[j] = o;
        }
    }
}

// ---------------- Kernel 2: MFMA gemm, barrier-free K loop ----------------
// block = (o_tile 64, row_tile 16, bank); 4 waves, each wave does a 16x16 D tile.
// A and B fragments are direct 16B global loads from row-major bf16 (layouts:
// A[m=lane&15][k=q*8+j], B[k=q*8+j][n=lane&15]=W[n][k], both contiguous in k).
__global__ __launch_bounds__(256) void mfma_gemm(
    const ushort* __restrict__ xb, const ushort* __restrict__ Wb,
    const float* __restrict__ bias, const int* __restrict__ counts,
    const int* __restrict__ lists, float* __restrict__ out, int nrows_total)
{
    int bank = blockIdx.z;
    int nrows = counts[bank];
    int row0 = blockIdx.y * 16;
    if (row0 >= nrows) return;

    __shared__ int ridx[16];
    int t = threadIdx.x;
    if (t < 16) {
        int r = row0 + t;
        ridx[t] = lists[bank * nrows_total + ((r < nrows) ? r : 0)];
    }
    __syncthreads();

    int lane = t & 63;
    int wave = t >> 6;
    int ln = lane & 15;   // A: row m   | B: out col n
    int q  = lane >> 4;   // k-quad: k offset = q*8

    int o_glob = blockIdx.x * 64 + wave * 16 + ln;
    const ushort* ap = xb + (size_t)ridx[ln] * INF + q * 8;
    const ushort* bp = Wb + ((size_t)bank * OUTF + o_glob) * INF + q * 8;

    f32x4 acc = {0.f, 0.f, 0.f, 0.f};
#pragma unroll 4
    for (int k = 0; k < INF; k += 32) {
        bf16x8 a = *(const bf16x8*)ap; ap += 32;
        bf16x8 b = *(const bf16x8*)bp; bp += 32;
        acc = __builtin_amdgcn_mfma_f32_16x16x32_bf16(a, b, acc, 0, 0, 0);
    }

    float bv = bias[bank * OUTF + o_glob];
#pragma unroll
    for (int r = 0; r < 4; ++r) {
        int m = q * 4 + r;   // C/D: row = q*4 + reg, col = lane&15
        if (row0 + m < nrows)
            out[(size_t)ridx[m] * OUTF + o_glob] = acc[r] + bv;
    }
}

// ---------------- fp32 fallback (used only if ws too small) ----------------
__global__ void bucket_kernel(const int* __restrict__ sel, int* __restrict__ counts,
                              int* __restrict__ lists, int nrows) {
    int t = threadIdx.x;
    if (t < NB) counts[t] = 0;
    __syncthreads();
    for (int r = t; r < nrows; r += blockDim.x) {
        int b = sel[r];
        int pos = atomicAdd(&counts[b], 1);
        lists[b * nrows + pos] = r;
    }
}

#define MR 64
#define NT 64
#define KT 32
#define PAD 36

__global__ __launch_bounds__(256) void banked_gemm(
    const float* __restrict__ x, const float* __restrict__ W,
    const float* __restrict__ bias, const int* __restrict__ counts,
    const int* __restrict__ lists, float* __restrict__ out, int nrows_total) {
    int bank = blockIdx.z;
    int nrows = counts[bank];
    int row0 = blockIdx.y * MR;
    if (row0 >= nrows) return;

    __shared__ float xs[MR][PAD];
    __shared__ float ws[NT][PAD];
    __shared__ int ridx[MR];

    int t = threadIdx.x;
    if (t < MR) {
        int r = row0 + t;
        ridx[t] = (r < nrows) ? lists[bank * nrows_total + r] : -1;
    }
    __syncthreads();

    int tx = t & 15;
    int ty = t >> 4;
    int o_base = blockIdx.x * NT;
    const float* Wb = W + (size_t)bank * OUTF * INF;

    float acc[4][4] = {};
    int lr = t >> 3;
    int lk = (t & 7) * 4;
    int wo = t >> 2;
    int wk = (t & 3) * 8;
    int rg0 = ridx[lr];
    int rg1 = ridx[lr + 32];

    for (int kt = 0; kt < INF; kt += KT) {
        __syncthreads();
        float4 xv0 = make_float4(0.f, 0.f, 0.f, 0.f);
        float4 xv1 = xv0;
        if (rg0 >= 0) xv0 = *(const float4*)(x + (size_t)rg0 * INF + kt + lk);
        if (rg1 >= 0) xv1 = *(const float4*)(x + (size_t)rg1 * INF + kt + lk);
        *(float4*)&xs[lr][lk]      = xv0;
        *(float4*)&xs[lr + 32][lk] = xv1;
        const float* wp = Wb + (size_t)(o_base + wo) * INF + kt + wk;
        *(float4*)&ws[wo][wk]     = *(const float4*)wp;
        *(float4*)&ws[wo][wk + 4] = *(const float4*)(wp + 4);
        __syncthreads();

#pragma unroll
        for (int k = 0; k < KT; k += 4) {
            float4 a[4], w[4];
#pragma unroll
            for (int ri = 0; ri < 4; ++ri) a[ri] = *(float4*)&xs[ty + 16 * ri][k];
#pragma unroll
            for (int oi = 0; oi < 4; ++oi) w[oi] = *(float4*)&ws[tx + 16 * oi][k];
#pragma unroll
            for (int ri = 0; ri < 4; ++ri)
#pragma unroll
                for (int oi = 0; oi < 4; ++oi)
                    acc[ri][oi] += a[ri].x * w[oi].x + a[ri].y * w[oi].y
                                 + a[ri].z * w[oi].z + a[ri].w * w[oi].w;
        }
    }

#pragma unroll
    for (int oi = 0; oi < 4; ++oi) {
        float bv = bias[bank * OUTF + o_base + tx + 16 * oi];
#pragma unroll
        for (int ri = 0; ri < 4; ++ri) acc[ri][oi] += bv;
    }

#pragma unroll
    for (int ri = 0; ri < 4; ++ri) {
        int rl = ty + 16 * ri;
        if (row0 + rl < nrows) {
            int rg = ridx[rl];
            float* op = out + (size_t)rg * OUTF + o_base;
#pragma unroll
            for (int oi = 0; oi < 4; ++oi) op[tx + 16 * oi] = acc[ri][oi];
        }
    }
}

extern "C" void kernel_launch(void* const* d_in, const int* in_sizes, int n_in,
                              void* d_out, int out_size, void* d_ws, size_t ws_size,
                              hipStream_t stream) {
    const float* tensor = (const float*)d_in[0];   // (B,S,K,IN) fp32
    const int*   sel    = (const int*)d_in[1];     // (B,S,K) int32
    const float* weight = (const float*)d_in[2];   // (NB,OUT,IN) fp32
    const float* bias   = (const float*)d_in[3];   // (NB,OUT) fp32
    float* out = (float*)d_out;

    int nrows = in_sizes[1];                       // B*S*K = 1024

    // ws layout: counts[NB] | lists[NB*nrows] | xb bf16 | Wb bf16
    int* counts = (int*)d_ws;
    int* lists  = counts + NB;
    size_t int_bytes = (size_t)(NB + NB * nrows) * sizeof(int);
    size_t xb_bytes  = (size_t)nrows * INF * sizeof(ushort);
    size_t wb_bytes  = (size_t)NB * OUTF * INF * sizeof(ushort);
    size_t need = int_bytes + xb_bytes + wb_bytes;

    if (ws_size >= need) {
        ushort* xb = (ushort*)((char*)d_ws + int_bytes);
        ushort* Wb = (ushort*)((char*)d_ws + int_bytes + xb_bytes);

        prep_kernel<<<1025, 256, 0, stream>>>(tensor, sel, weight, counts, lists,
                                              xb, Wb, nrows);
        dim3 grid(OUTF / 64, (nrows + 15) / 16, NB);
        mfma_gemm<<<grid, 256, 0, stream>>>(xb, Wb, bias, counts, lists, out, nrows);
    } else {
        bucket_kernel<<<1, 1024, 0, stream>>>(sel, counts, lists, nrows);
        dim3 grid(OUTF / NT, (nrows + MR - 1) / MR, NB);
        banked_gemm<<<grid, 256, 0, stream>>>(tensor, weight, bias, counts, lists,
                                              out, nrows);
    }
}

// Round 3
// 104.417 us; speedup vs baseline: 1.8492x; 1.8492x over previous
//
#include <hip/hip_runtime.h>

#define NB   16
#define INF  512
#define OUTF 512

typedef __attribute__((ext_vector_type(8))) short bf16x8;
typedef __attribute__((ext_vector_type(4))) float f32x4;

static __device__ __forceinline__ ushort f2bf(float f) {
    unsigned u = __float_as_uint(f);
    u += 0x7FFFu + ((u >> 16) & 1u);   // round-to-nearest-even
    return (ushort)(u >> 16);
}

// ---------------- Kernel 1: prep ----------------
// block 0           : bucket rows by bank via LDS atomics (order within a bank
//                     is irrelevant -- each row's output is independent)
// blocks 1..gridDim : convert W then x to bf16 (grid-stride float4 -> ushort4)
__global__ __launch_bounds__(256) void prep_kernel(
    const float* __restrict__ x, const int* __restrict__ sel,
    const float* __restrict__ W,
    int* __restrict__ counts, int* __restrict__ lists,
    ushort* __restrict__ xb, ushort* __restrict__ Wb, int nrows)
{
    int t = threadIdx.x;
    if (blockIdx.x == 0) {
        __shared__ int cnt[NB];
        if (t < NB) cnt[t] = 0;
        __syncthreads();
        for (int r = t; r < nrows; r += 256) {
            int b = sel[r];
            int pos = atomicAdd(&cnt[b], 1);
            lists[b * nrows + pos] = r;
        }
        __syncthreads();
        if (t < NB) counts[t] = cnt[t];
        return;
    }
    const int nvw = NB * OUTF * INF / 4;
    const int nvx = (nrows * INF) / 4;
    int gid = (blockIdx.x - 1) * 256 + t;
    int stride = (gridDim.x - 1) * 256;
    const float4* Wf = (const float4*)W;
    const float4* xf = (const float4*)x;
    ushort4* Wo = (ushort4*)Wb;
    ushort4* xo = (ushort4*)xb;
    for (int i = gid; i < nvw + nvx; i += stride) {
        if (i < nvw) {
            float4 v = Wf[i];
            ushort4 o;
            o.x = f2bf(v.x); o.y = f2bf(v.y); o.z = f2bf(v.z); o.w = f2bf(v.w);
            Wo[i] = o;
        } else {
            int j = i - nvw;
            float4 v = xf[j];
            ushort4 o;
            o.x = f2bf(v.x); o.y = f2bf(v.y); o.z = f2bf(v.z); o.w = f2bf(v.w);
            xo[j] = o;
        }
    }
}

// ---------------- Kernel 2: MFMA gemm, barrier-free K loop ----------------
// block = (o_tile 64, row_tile 16, bank); 4 waves, each wave does a 16x16 D tile.
// A and B fragments are direct 16B global loads from row-major bf16 (layouts:
// A[m=lane&15][k=q*8+j], B[k=q*8+j][n=lane&15]=W[n][k], both contiguous in k).
__global__ __launch_bounds__(256) void mfma_gemm(
    const ushort* __restrict__ xb, const ushort* __restrict__ Wb,
    const float* __restrict__ bias, const int* __restrict__ counts,
    const int* __restrict__ lists, float* __restrict__ out, int nrows_total)
{
    int bank = blockIdx.z;
    int nrows = counts[bank];
    int row0 = blockIdx.y * 16;
    if (row0 >= nrows) return;

    __shared__ int ridx[16];
    int t = threadIdx.x;
    if (t < 16) {
        int r = row0 + t;
        ridx[t] = lists[bank * nrows_total + ((r < nrows) ? r : 0)];
    }
    __syncthreads();

    int lane = t & 63;
    int wave = t >> 6;
    int ln = lane & 15;   // A: row m   | B: out col n
    int q  = lane >> 4;   // k-quad: k offset = q*8

    int o_glob = blockIdx.x * 64 + wave * 16 + ln;
    const ushort* ap = xb + (size_t)ridx[ln] * INF + q * 8;
    const ushort* bp = Wb + ((size_t)bank * OUTF + o_glob) * INF + q * 8;

    f32x4 acc = {0.f, 0.f, 0.f, 0.f};
#pragma unroll 4
    for (int k = 0; k < INF; k += 32) {
        bf16x8 a = *(const bf16x8*)ap; ap += 32;
        bf16x8 b = *(const bf16x8*)bp; bp += 32;
        acc = __builtin_amdgcn_mfma_f32_16x16x32_bf16(a, b, acc, 0, 0, 0);
    }

    float bv = bias[bank * OUTF + o_glob];
#pragma unroll
    for (int r = 0; r < 4; ++r) {
        int m = q * 4 + r;   // C/D: row = q*4 + reg, col = lane&15
        if (row0 + m < nrows)
            out[(size_t)ridx[m] * OUTF + o_glob] = acc[r] + bv;
    }
}

extern "C" void kernel_launch(void* const* d_in, const int* in_sizes, int n_in,
                              void* d_out, int out_size, void* d_ws, size_t ws_size,
                              hipStream_t stream) {
    const float* tensor = (const float*)d_in[0];   // (B,S,K,IN) fp32
    const int*   sel    = (const int*)d_in[1];     // (B,S,K) int32
    const float* weight = (const float*)d_in[2];   // (NB,OUT,IN) fp32
    const float* bias   = (const float*)d_in[3];   // (NB,OUT) fp32
    float* out = (float*)d_out;

    int nrows = in_sizes[1];                       // B*S*K = 1024

    // ws layout: counts[NB] | lists[NB*nrows] | xb bf16 | Wb bf16
    int* counts = (int*)d_ws;
    int* lists  = counts + NB;
    size_t int_bytes = (size_t)(NB + NB * nrows) * sizeof(int);
    size_t xb_bytes  = (size_t)nrows * INF * sizeof(ushort);
    ushort* xb = (ushort*)((char*)d_ws + int_bytes);
    ushort* Wb = (ushort*)((char*)d_ws + int_bytes + xb_bytes);

    prep_kernel<<<1025, 256, 0, stream>>>(tensor, sel, weight, counts, lists,
                                          xb, Wb, nrows);
    dim3 grid(OUTF / 64, (nrows + 15) / 16, NB);
    mfma_gemm<<<grid, 256, 0, stream>>>(xb, Wb, bias, counts, lists, out, nrows);
}

// Round 4
// 87.465 us; speedup vs baseline: 2.2076x; 1.1938x over previous
//
#include <hip/hip_runtime.h>

#define NB   16
#define INF  512
#define OUTF 512
#define MAXT 128   // max (bank,row-tile) work items: sum ceil(c_b/16) <= 79

typedef __attribute__((ext_vector_type(8))) short bf16x8;
typedef __attribute__((ext_vector_type(4))) float f32x4;

static __device__ __forceinline__ ushort f2bf(float f) {
    unsigned u = __float_as_uint(f);
    u += 0x7FFFu + ((u >> 16) & 1u);   // round-to-nearest-even
    return (ushort)(u >> 16);
}

// ws layout (ints): counts[16] | ntiles[1]+pad[15] | tiles[128] | lists[NB*nrows]
// then bf16: xb[nrows*INF] | Wb[NB*OUTF*INF]
#define HDR_INTS (16 + 16 + MAXT)

// ---------------- Kernel 1: prep ----------------
// block 0: bucket rows by bank via LDS atomics + emit flat tile worklist
// blocks 1..: convert W then x to bf16 (grid-stride float4 -> ushort4)
__global__ __launch_bounds__(256) void prep_kernel(
    const float* __restrict__ x, const int* __restrict__ sel,
    const float* __restrict__ W,
    int* __restrict__ counts, int* __restrict__ ntiles, int* __restrict__ tiles,
    int* __restrict__ lists,
    ushort* __restrict__ xb, ushort* __restrict__ Wb, int nrows)
{
    int t = threadIdx.x;
    if (blockIdx.x == 0) {
        __shared__ int cnt[NB];
        if (t < NB) cnt[t] = 0;
        __syncthreads();
        for (int r = t; r < nrows; r += 256) {
            int b = sel[r];
            int pos = atomicAdd(&cnt[b], 1);
            lists[b * nrows + pos] = r;
        }
        __syncthreads();
        if (t < NB) counts[t] = cnt[t];
        if (t == 0) {
            int nt = 0;
            for (int b = 0; b < NB; ++b)
                for (int r0 = 0; r0 < cnt[b]; r0 += 16)
                    tiles[nt++] = (b << 16) | r0;
            ntiles[0] = nt;
        }
        return;
    }
    const int nvw = NB * OUTF * INF / 4;
    const int nvx = (nrows * INF) / 4;
    int gid = (blockIdx.x - 1) * 256 + t;
    int stride = (gridDim.x - 1) * 256;
    const float4* Wf = (const float4*)W;
    const float4* xf = (const float4*)x;
    ushort4* Wo = (ushort4*)Wb;
    ushort4* xo = (ushort4*)xb;
    for (int i = gid; i < nvw + nvx; i += stride) {
        if (i < nvw) {
            float4 v = Wf[i];
            ushort4 o;
            o.x = f2bf(v.x); o.y = f2bf(v.y); o.z = f2bf(v.z); o.w = f2bf(v.w);
            Wo[i] = o;
        } else {
            int j = i - nvw;
            float4 v = xf[j];
            ushort4 o;
            o.x = f2bf(v.x); o.y = f2bf(v.y); o.z = f2bf(v.z); o.w = f2bf(v.w);
            xo[j] = o;
        }
    }
}

// ---------------- Kernel 2: MFMA gemm over flat tile list ----------------
// block = (o_tile 64 wide, tile y); tile = (bank, row0). 4 waves/block, each
// wave does a 16x16 D tile, K streamed with direct-to-fragment 16B loads.
__global__ __launch_bounds__(256) void mfma_gemm(
    const ushort* __restrict__ xb, const ushort* __restrict__ Wb,
    const float* __restrict__ bias, const int* __restrict__ counts,
    const int* __restrict__ ntiles, const int* __restrict__ tiles,
    const int* __restrict__ lists, float* __restrict__ out, int nrows_total)
{
    int y = blockIdx.y;
    if (y >= ntiles[0]) return;
    int tb = tiles[y];
    int bank = tb >> 16;
    int row0 = tb & 0xffff;
    int nrows = counts[bank];

    __shared__ int ridx[16];
    int t = threadIdx.x;
    if (t < 16) {
        int r = row0 + t;
        ridx[t] = lists[bank * nrows_total + ((r < nrows) ? r : 0)];
    }
    __syncthreads();

    int lane = t & 63;
    int wave = t >> 6;
    int ln = lane & 15;   // A: row m   | B: out col n
    int q  = lane >> 4;   // k-quad: k offset = q*8

    int o_glob = blockIdx.x * 64 + wave * 16 + ln;
    const ushort* ap = xb + (size_t)ridx[ln] * INF + q * 8;
    const ushort* bp = Wb + ((size_t)bank * OUTF + o_glob) * INF + q * 8;

    f32x4 acc = {0.f, 0.f, 0.f, 0.f};
#pragma unroll 8
    for (int k = 0; k < INF; k += 32) {
        bf16x8 a = *(const bf16x8*)ap; ap += 32;
        bf16x8 b = *(const bf16x8*)bp; bp += 32;
        acc = __builtin_amdgcn_mfma_f32_16x16x32_bf16(a, b, acc, 0, 0, 0);
    }

    float bv = bias[bank * OUTF + o_glob];
#pragma unroll
    for (int r = 0; r < 4; ++r) {
        int m = q * 4 + r;   // C/D: row = q*4 + reg, col = lane&15
        if (row0 + m < nrows)
            out[(size_t)ridx[m] * OUTF + o_glob] = acc[r] + bv;
    }
}

extern "C" void kernel_launch(void* const* d_in, const int* in_sizes, int n_in,
                              void* d_out, int out_size, void* d_ws, size_t ws_size,
                              hipStream_t stream) {
    const float* tensor = (const float*)d_in[0];   // (B,S,K,IN) fp32
    const int*   sel    = (const int*)d_in[1];     // (B,S,K) int32
    const float* weight = (const float*)d_in[2];   // (NB,OUT,IN) fp32
    const float* bias   = (const float*)d_in[3];   // (NB,OUT) fp32
    float* out = (float*)d_out;

    int nrows = in_sizes[1];                       // B*S*K = 1024

    int* counts = (int*)d_ws;
    int* ntiles = counts + 16;
    int* tiles  = ntiles + 16;
    int* lists  = (int*)d_ws + HDR_INTS;
    size_t int_bytes = (size_t)(HDR_INTS + NB * nrows) * sizeof(int);
    size_t xb_bytes  = (size_t)nrows * INF * sizeof(ushort);
    ushort* xb = (ushort*)((char*)d_ws + int_bytes);
    ushort* Wb = (ushort*)((char*)d_ws + int_bytes + xb_bytes);

    prep_kernel<<<1025, 256, 0, stream>>>(tensor, sel, weight, counts, ntiles,
                                          tiles, lists, xb, Wb, nrows);
    dim3 grid(OUTF / 64, MAXT, 1);
    mfma_gemm<<<grid, 256, 0, stream>>>(xb, Wb, bias, counts, ntiles, tiles,
                                        lists, out, nrows);
}